// Round 6
// baseline (358.430 us; speedup 1.0000x reference)
//
#include <hip/hip_runtime.h>

#define BN_EPS 1e-5f

typedef __bf16 bf16_t;
typedef __bf16 bf16x8 __attribute__((ext_vector_type(8)));
typedef float f32x4 __attribute__((ext_vector_type(4)));

// ws layout (bytes):
//   bnc   f32   3072 elems  @ 0
//   owtb  bf16  73728       @ 12288    [j pad32][kp 9][c 256]
//   off   f32   294912      @ 178176
//   xb    bf16  16777216    @ 1357824
//   w1b   bf16  262144      @ 34912256
//   w2fb  bf16  589824      @ 35436544   fragment order [kp][p][nt][lane][8]
//   w3b   bf16  262144      @ 36616192
//   h1b   bf16  4194304     @ 37140480   [b*hw][c=256]
//   h2b   bf16  4194304     @ 45529088
//   total ~51.4 MB

// ---------------- prep: BN scale/shift ----------------
__global__ void __launch_bounds__(1024) k_bnprep(
    const float* g1, const float* b1, const float* m1, const float* v1,
    const float* g2, const float* b2, const float* m2, const float* v2,
    const float* g3, const float* b3, const float* m3, const float* v3,
    float* bnc) {
    int t = threadIdx.x;
    if (t < 256) {
        float s = g1[t] * rsqrtf(v1[t] + BN_EPS);
        bnc[t] = s;
        bnc[256 + t] = b1[t] - m1[t] * s;
        float s2 = g2[t] * rsqrtf(v2[t] + BN_EPS);
        bnc[512 + t] = s2;
        bnc[768 + t] = b2[t] - m2[t] * s2;
    }
    float s3 = g3[t] * rsqrtf(v3[t] + BN_EPS);
    bnc[1024 + t] = s3;
    bnc[2048 + t] = b3[t] - m3[t] * s3;
}

// ---------------- prep: fp32 -> bf16 cast ----------------
__global__ void __launch_bounds__(256) k_cast(const float* __restrict__ s,
                                              bf16_t* __restrict__ d, int n4) {
    int i = blockIdx.x * 256 + threadIdx.x;
    if (i >= n4) return;
    float4 v = ((const float4*)s)[i];
    d[4 * i + 0] = (bf16_t)v.x;
    d[4 * i + 1] = (bf16_t)v.y;
    d[4 * i + 2] = (bf16_t)v.z;
    d[4 * i + 3] = (bf16_t)v.w;
}

// ---- prep: w2 (O,C,3,3) -> bf16 fragment order [kp][p][nt][lane][8] ----
// n = nt*16 + (lane&15), c = p*32 + (lane>>4)*8 + e. A wave's B-fragment
// load becomes base + lane*16B: one coalesced 1KB read, L2-broadcast-hot.
__global__ void __launch_bounds__(256) k_w2f(const float* __restrict__ w2,
                                             bf16_t* __restrict__ w2f) {
    int idx = blockIdx.x * 256 + threadIdx.x; // 9*8*16*64 = 73728 groups
    if (idx >= 73728) return;
    int lane = idx & 63;
    int rest = idx >> 6;   // kp*128 + p*16 + nt
    int nt = rest & 15;
    int rest2 = rest >> 4; // kp*8 + p
    int p = rest2 & 7;
    int kp = rest2 >> 3;
    int n = nt * 16 + (lane & 15);
    int c0 = p * 32 + (lane >> 4) * 8;
    bf16x8 r;
#pragma unroll
    for (int e = 0; e < 8; ++e)
        r[e] = (bf16_t)w2[(size_t)n * 2304 + (c0 + e) * 9 + kp];
    *(bf16x8*)(w2f + (size_t)idx * 8) = r;
}

// ---------------- prep: off_w (18,C,3,3) -> bf16 [j pad32][kp][c], 0-pad ----
__global__ void __launch_bounds__(256) k_owtb(const float* __restrict__ ow,
                                              bf16_t* __restrict__ owtb) {
    int idx = blockIdx.x * 256 + threadIdx.x; // 32*9*256 = 73728
    if (idx >= 73728) return;
    int j = idx / 2304;
    int rem = idx - j * 2304;
    int kp = rem >> 8;
    int c = rem & 255;
    float v = (j < 18) ? ow[(j * 256 + c) * 9 + kp] : 0.f;
    owtb[idx] = (bf16_t)v;
}

// ---------------- prep: x NCHW f32 -> xb NHWC bf16 ----------------
// grid (16 hw-tiles, 16 c-tiles, 16 b); 64c x 64hw tile via LDS
__global__ void __launch_bounds__(256) k_xb(const float* __restrict__ x,
                                            bf16_t* __restrict__ xb) {
    __shared__ float ld[64 * 68];
    int t = threadIdx.x;
    int hw0 = blockIdx.x * 64, c0 = blockIdx.y * 64, b = blockIdx.z;
    int ci = t >> 2, h0 = (t & 3) * 16;
    const float* src = x + ((size_t)(b * 1024 + c0 + ci) << 10) + hw0 + h0;
#pragma unroll
    for (int i = 0; i < 4; ++i)
        *(float4*)(ld + ci * 68 + h0 + 4 * i) = *(const float4*)(src + 4 * i);
    __syncthreads();
    int r = t >> 2, cc0 = (t & 3) * 16;
    bf16x8 o0, o1;
#pragma unroll
    for (int i = 0; i < 8; ++i) o0[i] = (bf16_t)ld[(cc0 + i) * 68 + r];
#pragma unroll
    for (int i = 0; i < 8; ++i) o1[i] = (bf16_t)ld[(cc0 + 8 + i) * 68 + r];
    bf16_t* dst = xb + ((size_t)(b * 1024 + hw0 + r) << 10) + c0 + cc0;
    *(bf16x8*)dst = o0;
    *(bf16x8*)(dst + 8) = o1;
}

// ---------------- shared MFMA GEMM: C[m][n] = A[m][K] * Bt[n][K]^T --------
// BM=64 BN=128 BK=32, 256 thr = 4 waves (2x2), wave: 32x64 (2x4 frags)
// epi 0: outb[m*ldo+n] = bf16(relu(acc*sc[n]+sh[n]))
// epi 1: outf NCHW fp32: relu(acc*sc[o]+sh[o] + resid), float4 rows
__global__ void __launch_bounds__(256) k_gemm64(
    const bf16_t* __restrict__ A, const bf16_t* __restrict__ Bt, int K, int ldo,
    const float* __restrict__ sc, const float* __restrict__ sh,
    const float* __restrict__ resid, bf16_t* __restrict__ outb,
    float* __restrict__ outf, int epi) {
    __shared__ __align__(16) bf16_t As[64 * 40];
    __shared__ __align__(16) bf16_t Bs[128 * 40];
    int t = threadIdx.x;
    int lane = t & 63;
    int w = t >> 6;
    int wm = w >> 1, wn = w & 1;
    int m0 = blockIdx.x * 64, n0 = blockIdx.y * 128;

    // staging maps
    int ar = t >> 2, as_ = t & 3;
    const bf16_t* ag = A + (size_t)(m0 + ar) * K + as_ * 8;
    int aw = ar * 40 + ((as_ ^ (ar & 3)) * 8);
    int bn0 = t >> 2, bs_ = t & 3;
    const bf16_t* bg0 = Bt + (size_t)(n0 + bn0) * K + bs_ * 8;
    const bf16_t* bg1 = Bt + (size_t)(n0 + 64 + bn0) * K + bs_ * 8;
    int bw0 = bn0 * 40 + ((bs_ ^ (bn0 & 3)) * 8);
    int bw1 = (64 + bn0) * 40 + ((bs_ ^ (bn0 & 3)) * 8);

    // fragment read offsets
    int asel = lane >> 4;
    int ar0 = wm * 32 + (lane & 15);
    int aoff0 = ar0 * 40 + ((asel ^ (ar0 & 3)) * 8);
    int aoff1 = (ar0 + 16) * 40 + ((asel ^ (ar0 & 3)) * 8);
    int boff[4];
#pragma unroll
    for (int ni = 0; ni < 4; ++ni) {
        int n = wn * 64 + ni * 16 + (lane & 15);
        boff[ni] = n * 40 + ((asel ^ (n & 3)) * 8);
    }
    f32x4 acc[2][4] = {};

    for (int k0 = 0; k0 < K; k0 += 32) {
        __syncthreads();
        *(bf16x8*)(As + aw) = *(const bf16x8*)(ag + k0);
        *(bf16x8*)(Bs + bw0) = *(const bf16x8*)(bg0 + k0);
        *(bf16x8*)(Bs + bw1) = *(const bf16x8*)(bg1 + k0);
        __syncthreads();
        bf16x8 a0 = *(const bf16x8*)(As + aoff0);
        bf16x8 a1 = *(const bf16x8*)(As + aoff1);
#pragma unroll
        for (int ni = 0; ni < 4; ++ni) {
            bf16x8 bv = *(const bf16x8*)(Bs + boff[ni]);
            acc[0][ni] = __builtin_amdgcn_mfma_f32_16x16x32_bf16(a0, bv, acc[0][ni], 0, 0, 0);
            acc[1][ni] = __builtin_amdgcn_mfma_f32_16x16x32_bf16(a1, bv, acc[1][ni], 0, 0, 0);
        }
    }

    int mrb = m0 + wm * 32 + (lane >> 4) * 4;
    int ncb = n0 + wn * 64 + (lane & 15);
    if (epi == 0) {
#pragma unroll
        for (int mi = 0; mi < 2; ++mi)
#pragma unroll
            for (int ni = 0; ni < 4; ++ni) {
                int n = ncb + ni * 16;
                float s = sc[n], h = sh[n];
#pragma unroll
                for (int j = 0; j < 4; ++j) {
                    int m = mrb + mi * 16 + j;
                    float v = fmaxf(fmaf(acc[mi][ni][j], s, h), 0.f);
                    outb[(size_t)m * ldo + n] = (bf16_t)v;
                }
            }
    } else {
#pragma unroll
        for (int mi = 0; mi < 2; ++mi) {
            int m = mrb + mi * 16;
            int bb = m >> 10, hw = m & 1023;
#pragma unroll
            for (int ni = 0; ni < 4; ++ni) {
                int o = ncb + ni * 16;
                float s = sc[o], h = sh[o];
                size_t idx = (((size_t)(bb * 1024 + o)) << 10) + hw;
                float4 r = *(const float4*)(resid + idx);
                float4 v;
                v.x = fmaxf(fmaf(acc[mi][ni][0], s, h) + r.x, 0.f);
                v.y = fmaxf(fmaf(acc[mi][ni][1], s, h) + r.y, 0.f);
                v.z = fmaxf(fmaf(acc[mi][ni][2], s, h) + r.z, 0.f);
                v.w = fmaxf(fmaf(acc[mi][ni][3], s, h) + r.w, 0.f);
                *(float4*)(outf + idx) = v;
            }
        }
    }
}

// ---------------- K2: 3x3 offset conv, MFMA, no LDS ----------------
// grid (32 y, 16 b), 256 thr = 4 waves; wave w -> (mi = x-half, ni = j-half)
// M=32 (x), N=32 (j, 18 real), K=2304 (9 taps x 256 c). A frags read direct
// from h1 (L2-hot) with boundary zero-masking; B frags from zero-padded owtb.
__global__ void __launch_bounds__(256) k_off(const bf16_t* __restrict__ h1,
                                             const bf16_t* __restrict__ owtb,
                                             const float* __restrict__ offb,
                                             float* __restrict__ off) {
    int t = threadIdx.x;
    int lane = t & 63;
    int w = t >> 6;
    int mi = w >> 1, ni = w & 1;
    int y = blockIdx.x, b = blockIdx.y;
    int x = (lane & 15) + mi * 16;
    int ksel = lane >> 4;
    int j = (lane & 15) + ni * 16;
    f32x4 acc = {};
    const bf16_t* h1base = h1 + ((size_t)b << 18);
    const bf16_t* brow = owtb + (size_t)j * 2304 + ksel * 8;

    for (int kp = 0; kp < 9; ++kp) {
        int yy = y + kp / 3 - 1;
        int xx = x + kp % 3 - 1;
        bool vy = (yy >= 0) && (yy < 32);
        bool vx = (xx >= 0) && (xx < 32);
        const bf16_t* arow = h1base + (((size_t)(yy * 32 + xx)) << 8) + ksel * 8;
        const bf16_t* bp = brow + kp * 256;
#pragma unroll
        for (int s = 0; s < 8; ++s) {
            bf16x8 av = {};
            if (vy && vx) av = *(const bf16x8*)(arow + s * 32);
            bf16x8 bv = *(const bf16x8*)(bp + s * 32);
            acc = __builtin_amdgcn_mfma_f32_16x16x32_bf16(av, bv, acc, 0, 0, 0);
        }
    }
    if (j < 18) {
        float bias = offb[j];
        size_t ob = (size_t)b * 18432 + (size_t)j * 1024 + y * 32 + mi * 16;
#pragma unroll
        for (int r = 0; r < 4; ++r) {
            off[ob + ksel * 4 + r] = acc[r] + bias;
        }
    }
}

// ---------------- K3: deformable conv, MFMA, coalesced B fragments --------
// grid (32 y, 16 b), 256 thr = 4 waves (wave wn owns n-range wn*64..+64).
// Per tap k: build samp As (8 panels [32][40]+8pad, XOR swizzle), barrier,
// 8 unrolled K-chunks: A from LDS, B from fragment-ordered w2f -- each
// B-fragment load is a contiguous 1KB wave read (base + lane*16B), L2-hot.
__global__ void __launch_bounds__(256) k_deform(const bf16_t* __restrict__ h1,
                                                const float* __restrict__ off,
                                                const bf16_t* __restrict__ w2f,
                                                const float* __restrict__ bnc,
                                                bf16_t* __restrict__ h2) {
    __shared__ __align__(16) bf16_t As[8 * 1288]; // 8 panels x ([32][40] + 8)
    int t = threadIdx.x;
    int lane = t & 63;
    int wn = t >> 6;
    int y = blockIdx.x, b = blockIdx.y;
    int sx = t >> 3, scg = t & 7; // sample-build: row, c-group of 32
    int asel = lane >> 4;
    int ar0 = lane & 15;
    // A read offsets within a panel (proven gemm64 map)
    int aoff0 = ar0 * 40 + ((asel ^ (ar0 & 3)) * 8);
    int aoff1 = (ar0 + 16) * 40 + ((asel ^ ((ar0 + 16) & 3)) * 8);
    // B fragment base: w2f[((kp*8+p)*16 + wn*4+ni)*64 + lane][8]
    const bf16_t* wfl = w2f + (size_t)(wn * 256 + lane) * 8;
    f32x4 acc[2][4] = {};
    size_t obase = (size_t)b * 18432 + (size_t)y * 32 + sx;
    size_t h1row = (size_t)b * 1024;

    for (int k = 0; k < 9; ++k) {
        __syncthreads(); // previous tap's readers done with As
        // ---- build bilinear-sampled tile (bf16) into panels ----
        float oy = off[obase + (size_t)(2 * k) * 1024];
        float ox = off[obase + (size_t)(2 * k + 1) * 1024];
        float py = (float)y + (float)(k / 3 - 1) + oy;
        float px = (float)sx + (float)(k % 3 - 1) + ox;
        float fy = floorf(py), fx = floorf(px);
        float wy = py - fy, wx = px - fx;
        int y0 = (int)fy, x0 = (int)fx;
        int y1 = y0 + 1, x1 = x0 + 1;
        float vy0 = (y0 >= 0 && y0 < 32) ? 1.f : 0.f;
        float vy1 = (y1 >= 0 && y1 < 32) ? 1.f : 0.f;
        float vx0 = (x0 >= 0 && x0 < 32) ? 1.f : 0.f;
        float vx1 = (x1 >= 0 && x1 < 32) ? 1.f : 0.f;
        int yc0 = min(max(y0, 0), 31), yc1 = min(max(y1, 0), 31);
        int xc0 = min(max(x0, 0), 31), xc1 = min(max(x1, 0), 31);
        float w00 = (1.f - wy) * (1.f - wx) * vy0 * vx0;
        float w01 = (1.f - wy) * wx * vy0 * vx1;
        float w10 = wy * (1.f - wx) * vy1 * vx0;
        float w11 = wy * wx * vy1 * vx1;
        const bf16_t* p00 = h1 + ((h1row + yc0 * 32 + xc0) << 8);
        const bf16_t* p01 = h1 + ((h1row + yc0 * 32 + xc1) << 8);
        const bf16_t* p10 = h1 + ((h1row + yc1 * 32 + xc0) << 8);
        const bf16_t* p11 = h1 + ((h1row + yc1 * 32 + xc1) << 8);
        bf16_t* pnl = As + scg * 1288 + sx * 40;
#pragma unroll
        for (int q = 0; q < 4; ++q) {
            int c = scg * 32 + q * 8;
            bf16x8 v00 = *(const bf16x8*)(p00 + c);
            bf16x8 v01 = *(const bf16x8*)(p01 + c);
            bf16x8 v10 = *(const bf16x8*)(p10 + c);
            bf16x8 v11 = *(const bf16x8*)(p11 + c);
            bf16x8 r;
#pragma unroll
            for (int e = 0; e < 8; ++e) {
                float f = w00 * (float)v00[e] + w01 * (float)v01[e] +
                          w10 * (float)v10[e] + w11 * (float)v11[e];
                r[e] = (bf16_t)f;
            }
            *(bf16x8*)(pnl + ((q ^ (sx & 3)) * 8)) = r;
        }
        __syncthreads(); // As ready for all waves
        // ---- GEMM over c: 8 chunks of 32, no barriers ----
#pragma unroll
        for (int p = 0; p < 8; ++p) {
            const bf16_t* pb = As + p * 1288;
            bf16x8 a0 = *(const bf16x8*)(pb + aoff0);
            bf16x8 a1 = *(const bf16x8*)(pb + aoff1);
            const bf16_t* wf = wfl + (size_t)(k * 8 + p) * 8192;
#pragma unroll
            for (int ni = 0; ni < 4; ++ni) {
                bf16x8 bv = *(const bf16x8*)(wf + ni * 512);
                acc[0][ni] = __builtin_amdgcn_mfma_f32_16x16x32_bf16(a0, bv, acc[0][ni], 0, 0, 0);
                acc[1][ni] = __builtin_amdgcn_mfma_f32_16x16x32_bf16(a1, bv, acc[1][ni], 0, 0, 0);
            }
        }
    }
    // epilogue: BN2 + ReLU -> h2 bf16
    int mrb = (lane >> 4) * 4;
    int ncb = wn * 64 + (lane & 15);
#pragma unroll
    for (int mi = 0; mi < 2; ++mi)
#pragma unroll
        for (int ni = 0; ni < 4; ++ni) {
            int n = ncb + ni * 16;
            float s = bnc[512 + n], h = bnc[768 + n];
#pragma unroll
            for (int j = 0; j < 4; ++j) {
                int row = mrb + mi * 16 + j;
                float v = fmaxf(fmaf(acc[mi][ni][j], s, h), 0.f);
                h2[(((size_t)(b * 1024 + y * 32 + row)) << 8) + n] = (bf16_t)v;
            }
        }
}

extern "C" void kernel_launch(void* const* d_in, const int* in_sizes, int n_in,
                              void* d_out, int out_size, void* d_ws, size_t ws_size,
                              hipStream_t stream) {
    const float* x = (const float*)d_in[0];
    const float* w1 = (const float*)d_in[1];
    const float* bn1g = (const float*)d_in[2];
    const float* bn1b = (const float*)d_in[3];
    const float* bn1m = (const float*)d_in[4];
    const float* bn1v = (const float*)d_in[5];
    const float* off_w = (const float*)d_in[6];
    const float* off_b = (const float*)d_in[7];
    const float* w2 = (const float*)d_in[8];
    const float* bn2g = (const float*)d_in[9];
    const float* bn2b = (const float*)d_in[10];
    const float* bn2m = (const float*)d_in[11];
    const float* bn2v = (const float*)d_in[12];
    const float* w3 = (const float*)d_in[13];
    const float* bn3g = (const float*)d_in[14];
    const float* bn3b = (const float*)d_in[15];
    const float* bn3m = (const float*)d_in[16];
    const float* bn3v = (const float*)d_in[17];
    float* out = (float*)d_out;

    char* ws = (char*)d_ws;
    float* bnc = (float*)(ws + 0);
    bf16_t* owtb = (bf16_t*)(ws + 12288);
    float* off = (float*)(ws + 178176);
    bf16_t* xb = (bf16_t*)(ws + 1357824);
    bf16_t* w1b = (bf16_t*)(ws + 34912256);
    bf16_t* w2fb = (bf16_t*)(ws + 35436544);
    bf16_t* w3b = (bf16_t*)(ws + 36616192);
    bf16_t* h1b = (bf16_t*)(ws + 37140480);
    bf16_t* h2b = (bf16_t*)(ws + 45529088);

    k_bnprep<<<1, 1024, 0, stream>>>(bn1g, bn1b, bn1m, bn1v, bn2g, bn2b, bn2m,
                                     bn2v, bn3g, bn3b, bn3m, bn3v, bnc);
    k_cast<<<256, 256, 0, stream>>>(w1, w1b, 65536);
    k_cast<<<256, 256, 0, stream>>>(w3, w3b, 65536);
    k_w2f<<<288, 256, 0, stream>>>(w2, w2fb);
    k_owtb<<<288, 256, 0, stream>>>(off_w, owtb);
    k_xb<<<dim3(16, 16, 16), 256, 0, stream>>>(x, xb);
    // conv1: M=16384 N=256 K=1024
    k_gemm64<<<dim3(256, 2), 256, 0, stream>>>(xb, w1b, 1024, 256, bnc,
                                               bnc + 256, nullptr, h1b, nullptr, 0);
    k_off<<<dim3(32, 16), 256, 0, stream>>>(h1b, owtb, off_b, off);
    k_deform<<<dim3(32, 16), 256, 0, stream>>>(h1b, off, w2fb, bnc, h2b);
    // conv3: M=16384 N=1024 K=256, residual + BN3 + ReLU -> out NCHW f32
    k_gemm64<<<dim3(256, 8), 256, 0, stream>>>(h2b, w3b, 256, 1024, bnc + 1024,
                                               bnc + 2048, x, nullptr, out, 1);
}

// Round 7
// 294.262 us; speedup vs baseline: 1.2181x; 1.2181x over previous
//
#include <hip/hip_runtime.h>

#define BN_EPS 1e-5f

typedef __bf16 bf16_t;
typedef __bf16 bf16x8 __attribute__((ext_vector_type(8)));
typedef float f32x4 __attribute__((ext_vector_type(4)));

// ws layout (bytes):
//   bnc   f32   3072 elems  @ 0
//   owtb  bf16  73728       @ 12288    [j pad32][kp 9][c 256]
//   off   f32   294912      @ 178176
//   xb    bf16  16777216    @ 1357824
//   w1b   bf16  262144      @ 34912256
//   w2fb  bf16  589824      @ 35436544   fragment order [kp][p][nt][lane][8]
//   w3b   bf16  262144      @ 36616192
//   h1b   bf16  4194304     @ 37140480   [b*hw][c=256]
//   h2b   bf16  4194304     @ 45529088
//   total ~51.4 MB

// ---------------- prep: BN scale/shift ----------------
__global__ void __launch_bounds__(1024) k_bnprep(
    const float* g1, const float* b1, const float* m1, const float* v1,
    const float* g2, const float* b2, const float* m2, const float* v2,
    const float* g3, const float* b3, const float* m3, const float* v3,
    float* bnc) {
    int t = threadIdx.x;
    if (t < 256) {
        float s = g1[t] * rsqrtf(v1[t] + BN_EPS);
        bnc[t] = s;
        bnc[256 + t] = b1[t] - m1[t] * s;
        float s2 = g2[t] * rsqrtf(v2[t] + BN_EPS);
        bnc[512 + t] = s2;
        bnc[768 + t] = b2[t] - m2[t] * s2;
    }
    float s3 = g3[t] * rsqrtf(v3[t] + BN_EPS);
    bnc[1024 + t] = s3;
    bnc[2048 + t] = b3[t] - m3[t] * s3;
}

// ---------------- prep: fp32 -> bf16 cast ----------------
__global__ void __launch_bounds__(256) k_cast(const float* __restrict__ s,
                                              bf16_t* __restrict__ d, int n4) {
    int i = blockIdx.x * 256 + threadIdx.x;
    if (i >= n4) return;
    float4 v = ((const float4*)s)[i];
    d[4 * i + 0] = (bf16_t)v.x;
    d[4 * i + 1] = (bf16_t)v.y;
    d[4 * i + 2] = (bf16_t)v.z;
    d[4 * i + 3] = (bf16_t)v.w;
}

// ---- prep: w2 (O,C,3,3) -> bf16 fragment order [kp][p][nt][lane][8] ----
__global__ void __launch_bounds__(256) k_w2f(const float* __restrict__ w2,
                                             bf16_t* __restrict__ w2f) {
    int idx = blockIdx.x * 256 + threadIdx.x; // 9*8*16*64 = 73728 groups
    if (idx >= 73728) return;
    int lane = idx & 63;
    int rest = idx >> 6;   // kp*128 + p*16 + nt
    int nt = rest & 15;
    int rest2 = rest >> 4; // kp*8 + p
    int p = rest2 & 7;
    int kp = rest2 >> 3;
    int n = nt * 16 + (lane & 15);
    int c0 = p * 32 + (lane >> 4) * 8;
    bf16x8 r;
#pragma unroll
    for (int e = 0; e < 8; ++e)
        r[e] = (bf16_t)w2[(size_t)n * 2304 + (c0 + e) * 9 + kp];
    *(bf16x8*)(w2f + (size_t)idx * 8) = r;
}

// ---------------- prep: off_w (18,C,3,3) -> bf16 [j pad32][kp][c], 0-pad ----
__global__ void __launch_bounds__(256) k_owtb(const float* __restrict__ ow,
                                              bf16_t* __restrict__ owtb) {
    int idx = blockIdx.x * 256 + threadIdx.x; // 32*9*256 = 73728
    if (idx >= 73728) return;
    int j = idx / 2304;
    int rem = idx - j * 2304;
    int kp = rem >> 8;
    int c = rem & 255;
    float v = (j < 18) ? ow[(j * 256 + c) * 9 + kp] : 0.f;
    owtb[idx] = (bf16_t)v;
}

// ---------------- prep: x NCHW f32 -> xb NHWC bf16 ----------------
__global__ void __launch_bounds__(256) k_xb(const float* __restrict__ x,
                                            bf16_t* __restrict__ xb) {
    __shared__ float ld[64 * 68];
    int t = threadIdx.x;
    int hw0 = blockIdx.x * 64, c0 = blockIdx.y * 64, b = blockIdx.z;
    int ci = t >> 2, h0 = (t & 3) * 16;
    const float* src = x + ((size_t)(b * 1024 + c0 + ci) << 10) + hw0 + h0;
#pragma unroll
    for (int i = 0; i < 4; ++i)
        *(float4*)(ld + ci * 68 + h0 + 4 * i) = *(const float4*)(src + 4 * i);
    __syncthreads();
    int r = t >> 2, cc0 = (t & 3) * 16;
    bf16x8 o0, o1;
#pragma unroll
    for (int i = 0; i < 8; ++i) o0[i] = (bf16_t)ld[(cc0 + i) * 68 + r];
#pragma unroll
    for (int i = 0; i < 8; ++i) o1[i] = (bf16_t)ld[(cc0 + 8 + i) * 68 + r];
    bf16_t* dst = xb + ((size_t)(b * 1024 + hw0 + r) << 10) + c0 + cc0;
    *(bf16x8*)dst = o0;
    *(bf16x8*)(dst + 8) = o1;
}

// ---------------- shared MFMA GEMM: C[m][n] = A[m][K] * Bt[n][K]^T --------
__global__ void __launch_bounds__(256) k_gemm64(
    const bf16_t* __restrict__ A, const bf16_t* __restrict__ Bt, int K, int ldo,
    const float* __restrict__ sc, const float* __restrict__ sh,
    const float* __restrict__ resid, bf16_t* __restrict__ outb,
    float* __restrict__ outf, int epi) {
    __shared__ __align__(16) bf16_t As[64 * 40];
    __shared__ __align__(16) bf16_t Bs[128 * 40];
    int t = threadIdx.x;
    int lane = t & 63;
    int w = t >> 6;
    int wm = w >> 1, wn = w & 1;
    int m0 = blockIdx.x * 64, n0 = blockIdx.y * 128;

    int ar = t >> 2, as_ = t & 3;
    const bf16_t* ag = A + (size_t)(m0 + ar) * K + as_ * 8;
    int aw = ar * 40 + ((as_ ^ (ar & 3)) * 8);
    int bn0 = t >> 2, bs_ = t & 3;
    const bf16_t* bg0 = Bt + (size_t)(n0 + bn0) * K + bs_ * 8;
    const bf16_t* bg1 = Bt + (size_t)(n0 + 64 + bn0) * K + bs_ * 8;
    int bw0 = bn0 * 40 + ((bs_ ^ (bn0 & 3)) * 8);
    int bw1 = (64 + bn0) * 40 + ((bs_ ^ (bn0 & 3)) * 8);

    int asel = lane >> 4;
    int ar0 = wm * 32 + (lane & 15);
    int aoff0 = ar0 * 40 + ((asel ^ (ar0 & 3)) * 8);
    int aoff1 = (ar0 + 16) * 40 + ((asel ^ (ar0 & 3)) * 8);
    int boff[4];
#pragma unroll
    for (int ni = 0; ni < 4; ++ni) {
        int n = wn * 64 + ni * 16 + (lane & 15);
        boff[ni] = n * 40 + ((asel ^ (n & 3)) * 8);
    }
    f32x4 acc[2][4] = {};

    for (int k0 = 0; k0 < K; k0 += 32) {
        __syncthreads();
        *(bf16x8*)(As + aw) = *(const bf16x8*)(ag + k0);
        *(bf16x8*)(Bs + bw0) = *(const bf16x8*)(bg0 + k0);
        *(bf16x8*)(Bs + bw1) = *(const bf16x8*)(bg1 + k0);
        __syncthreads();
        bf16x8 a0 = *(const bf16x8*)(As + aoff0);
        bf16x8 a1 = *(const bf16x8*)(As + aoff1);
#pragma unroll
        for (int ni = 0; ni < 4; ++ni) {
            bf16x8 bv = *(const bf16x8*)(Bs + boff[ni]);
            acc[0][ni] = __builtin_amdgcn_mfma_f32_16x16x32_bf16(a0, bv, acc[0][ni], 0, 0, 0);
            acc[1][ni] = __builtin_amdgcn_mfma_f32_16x16x32_bf16(a1, bv, acc[1][ni], 0, 0, 0);
        }
    }

    int mrb = m0 + wm * 32 + (lane >> 4) * 4;
    int ncb = n0 + wn * 64 + (lane & 15);
    if (epi == 0) {
#pragma unroll
        for (int mi = 0; mi < 2; ++mi)
#pragma unroll
            for (int ni = 0; ni < 4; ++ni) {
                int n = ncb + ni * 16;
                float s = sc[n], h = sh[n];
#pragma unroll
                for (int j = 0; j < 4; ++j) {
                    int m = mrb + mi * 16 + j;
                    float v = fmaxf(fmaf(acc[mi][ni][j], s, h), 0.f);
                    outb[(size_t)m * ldo + n] = (bf16_t)v;
                }
            }
    } else {
#pragma unroll
        for (int mi = 0; mi < 2; ++mi) {
            int m = mrb + mi * 16;
            int bb = m >> 10, hw = m & 1023;
#pragma unroll
            for (int ni = 0; ni < 4; ++ni) {
                int o = ncb + ni * 16;
                float s = sc[o], h = sh[o];
                size_t idx = (((size_t)(bb * 1024 + o)) << 10) + hw;
                float4 r = *(const float4*)(resid + idx);
                float4 v;
                v.x = fmaxf(fmaf(acc[mi][ni][0], s, h) + r.x, 0.f);
                v.y = fmaxf(fmaf(acc[mi][ni][1], s, h) + r.y, 0.f);
                v.z = fmaxf(fmaf(acc[mi][ni][2], s, h) + r.z, 0.f);
                v.w = fmaxf(fmaf(acc[mi][ni][3], s, h) + r.w, 0.f);
                *(float4*)(outf + idx) = v;
            }
        }
    }
}

// ---------------- K2: 3x3 offset conv, MFMA, no LDS ----------------
__global__ void __launch_bounds__(256) k_off(const bf16_t* __restrict__ h1,
                                             const bf16_t* __restrict__ owtb,
                                             const float* __restrict__ offb,
                                             float* __restrict__ off) {
    int t = threadIdx.x;
    int lane = t & 63;
    int w = t >> 6;
    int mi = w >> 1, ni = w & 1;
    int y = blockIdx.x, b = blockIdx.y;
    int x = (lane & 15) + mi * 16;
    int ksel = lane >> 4;
    int j = (lane & 15) + ni * 16;
    f32x4 acc = {};
    const bf16_t* h1base = h1 + ((size_t)b << 18);
    const bf16_t* brow = owtb + (size_t)j * 2304 + ksel * 8;

    for (int kp = 0; kp < 9; ++kp) {
        int yy = y + kp / 3 - 1;
        int xx = x + kp % 3 - 1;
        bool vy = (yy >= 0) && (yy < 32);
        bool vx = (xx >= 0) && (xx < 32);
        const bf16_t* arow = h1base + (((size_t)(yy * 32 + xx)) << 8) + ksel * 8;
        const bf16_t* bp = brow + kp * 256;
#pragma unroll
        for (int s = 0; s < 8; ++s) {
            bf16x8 av = {};
            if (vy && vx) av = *(const bf16x8*)(arow + s * 32);
            bf16x8 bv = *(const bf16x8*)(bp + s * 32);
            acc = __builtin_amdgcn_mfma_f32_16x16x32_bf16(av, bv, acc, 0, 0, 0);
        }
    }
    if (j < 18) {
        float bias = offb[j];
        size_t ob = (size_t)b * 18432 + (size_t)j * 1024 + y * 32 + mi * 16;
#pragma unroll
        for (int r = 0; r < 4; ++r) {
            off[ob + ksel * 4 + r] = acc[r] + bias;
        }
    }
}

// ---------------- K3: deformable conv, MFMA, pipelined ----------------
// grid (32 y, 16 b), 256 thr = 4 waves. Per tap k:
//   issue gather loads for tap k+1 (regs, latency hides under GEMM)
//   GEMM chunks 0-3 on As[cur] with depth-2 register B double-buffer
//   cvt + ds_write tap k+1 samples into As[cur^1]
//   GEMM chunks 4-7, then ONE barrier.
__global__ void __launch_bounds__(256) k_deform(const bf16_t* __restrict__ h1,
                                                const float* __restrict__ off,
                                                const bf16_t* __restrict__ w2f,
                                                const float* __restrict__ bnc,
                                                bf16_t* __restrict__ h2) {
    __shared__ __align__(16) bf16_t As[2][8 * 1288]; // 2 x 8 panels x ([32][40]+8)
    int t = threadIdx.x;
    int lane = t & 63;
    int wn = t >> 6;
    int y = blockIdx.x, b = blockIdx.y;
    int sx = t >> 3, scg = t & 7; // sample-build: row, c-group of 32
    int asel = lane >> 4;
    int ar0 = lane & 15;
    int aoff0 = ar0 * 40 + ((asel ^ (ar0 & 3)) * 8);
    int aoff1 = (ar0 + 16) * 40 + ((asel ^ ((ar0 + 16) & 3)) * 8);
    const bf16_t* wfl = w2f + (size_t)(wn * 256 + lane) * 8;
    f32x4 acc[2][4] = {};
    size_t obase = (size_t)b * 18432 + (size_t)y * 32 + sx;
    size_t h1row = (size_t)b * 1024;

    // pending-tap gather state (held in regs across the GEMM)
    bf16x8 g00[4], g01[4], g10[4], g11[4];
    float w00, w01, w10, w11;

    auto issue_gather = [&](int k) {
        float oy = off[obase + (size_t)(2 * k) * 1024];
        float ox = off[obase + (size_t)(2 * k + 1) * 1024];
        float py = (float)y + (float)(k / 3 - 1) + oy;
        float px = (float)sx + (float)(k % 3 - 1) + ox;
        float fy = floorf(py), fx = floorf(px);
        float wy = py - fy, wx = px - fx;
        int y0 = (int)fy, x0 = (int)fx;
        int y1 = y0 + 1, x1 = x0 + 1;
        float vy0 = (y0 >= 0 && y0 < 32) ? 1.f : 0.f;
        float vy1 = (y1 >= 0 && y1 < 32) ? 1.f : 0.f;
        float vx0 = (x0 >= 0 && x0 < 32) ? 1.f : 0.f;
        float vx1 = (x1 >= 0 && x1 < 32) ? 1.f : 0.f;
        int yc0 = min(max(y0, 0), 31), yc1 = min(max(y1, 0), 31);
        int xc0 = min(max(x0, 0), 31), xc1 = min(max(x1, 0), 31);
        w00 = (1.f - wy) * (1.f - wx) * vy0 * vx0;
        w01 = (1.f - wy) * wx * vy0 * vx1;
        w10 = wy * (1.f - wx) * vy1 * vx0;
        w11 = wy * wx * vy1 * vx1;
        const bf16_t* p00 = h1 + ((h1row + yc0 * 32 + xc0) << 8);
        const bf16_t* p01 = h1 + ((h1row + yc0 * 32 + xc1) << 8);
        const bf16_t* p10 = h1 + ((h1row + yc1 * 32 + xc0) << 8);
        const bf16_t* p11 = h1 + ((h1row + yc1 * 32 + xc1) << 8);
#pragma unroll
        for (int q = 0; q < 4; ++q) {
            int c = scg * 32 + q * 8;
            g00[q] = *(const bf16x8*)(p00 + c);
            g01[q] = *(const bf16x8*)(p01 + c);
            g10[q] = *(const bf16x8*)(p10 + c);
            g11[q] = *(const bf16x8*)(p11 + c);
        }
    };
    auto cvt_write = [&](int buf) {
        bf16_t* pnl = &As[buf][scg * 1288 + sx * 40];
#pragma unroll
        for (int q = 0; q < 4; ++q) {
            bf16x8 r;
#pragma unroll
            for (int e = 0; e < 8; ++e) {
                float f = w00 * (float)g00[q][e] + w01 * (float)g01[q][e] +
                          w10 * (float)g10[q][e] + w11 * (float)g11[q][e];
                r[e] = (bf16_t)f;
            }
            *(bf16x8*)(pnl + ((q ^ (sx & 3)) * 8)) = r;
        }
    };

    // prologue: fill buffer 0 for tap 0
    issue_gather(0);
    cvt_write(0);
    __syncthreads();

    for (int k = 0; k < 9; ++k) {
        int cur = k & 1;
        if (k < 8) issue_gather(k + 1); // loads in flight across GEMM
        const bf16_t* wfk = wfl + (size_t)k * 65536;
        bf16x8 bb[2][4];
#pragma unroll
        for (int ni = 0; ni < 4; ++ni)
            bb[0][ni] = *(const bf16x8*)(wfk + ni * 512);
#pragma unroll
        for (int ni = 0; ni < 4; ++ni)
            bb[1][ni] = *(const bf16x8*)(wfk + 8192 + ni * 512);
        // chunks 0..3
#pragma unroll
        for (int p = 0; p < 4; ++p) {
            const bf16_t* pb = &As[cur][p * 1288];
            bf16x8 a0 = *(const bf16x8*)(pb + aoff0);
            bf16x8 a1 = *(const bf16x8*)(pb + aoff1);
#pragma unroll
            for (int ni = 0; ni < 4; ++ni) {
                bf16x8 bv = bb[p & 1][ni];
                acc[0][ni] = __builtin_amdgcn_mfma_f32_16x16x32_bf16(a0, bv, acc[0][ni], 0, 0, 0);
                acc[1][ni] = __builtin_amdgcn_mfma_f32_16x16x32_bf16(a1, bv, acc[1][ni], 0, 0, 0);
            }
#pragma unroll
            for (int ni = 0; ni < 4; ++ni)
                bb[p & 1][ni] = *(const bf16x8*)(wfk + (p + 2) * 8192 + ni * 512);
        }
        // overlap: convert + stage next tap's samples into the other buffer
        if (k < 8) cvt_write(cur ^ 1);
        // chunks 4..7
#pragma unroll
        for (int p = 4; p < 8; ++p) {
            const bf16_t* pb = &As[cur][p * 1288];
            bf16x8 a0 = *(const bf16x8*)(pb + aoff0);
            bf16x8 a1 = *(const bf16x8*)(pb + aoff1);
#pragma unroll
            for (int ni = 0; ni < 4; ++ni) {
                bf16x8 bv = bb[p & 1][ni];
                acc[0][ni] = __builtin_amdgcn_mfma_f32_16x16x32_bf16(a0, bv, acc[0][ni], 0, 0, 0);
                acc[1][ni] = __builtin_amdgcn_mfma_f32_16x16x32_bf16(a1, bv, acc[1][ni], 0, 0, 0);
            }
            if (p + 2 < 8) {
#pragma unroll
                for (int ni = 0; ni < 4; ++ni)
                    bb[p & 1][ni] = *(const bf16x8*)(wfk + (p + 2) * 8192 + ni * 512);
            }
        }
        __syncthreads(); // writes to cur^1 visible; all reads of cur done
    }
    // epilogue: BN2 + ReLU -> h2 bf16
    int mrb = (lane >> 4) * 4;
    int ncb = wn * 64 + (lane & 15);
#pragma unroll
    for (int mi = 0; mi < 2; ++mi)
#pragma unroll
        for (int ni = 0; ni < 4; ++ni) {
            int n = ncb + ni * 16;
            float s = bnc[512 + n], h = bnc[768 + n];
#pragma unroll
            for (int j = 0; j < 4; ++j) {
                int row = mrb + mi * 16 + j;
                float v = fmaxf(fmaf(acc[mi][ni][j], s, h), 0.f);
                h2[(((size_t)(b * 1024 + y * 32 + row)) << 8) + n] = (bf16_t)v;
            }
        }
}

extern "C" void kernel_launch(void* const* d_in, const int* in_sizes, int n_in,
                              void* d_out, int out_size, void* d_ws, size_t ws_size,
                              hipStream_t stream) {
    const float* x = (const float*)d_in[0];
    const float* w1 = (const float*)d_in[1];
    const float* bn1g = (const float*)d_in[2];
    const float* bn1b = (const float*)d_in[3];
    const float* bn1m = (const float*)d_in[4];
    const float* bn1v = (const float*)d_in[5];
    const float* off_w = (const float*)d_in[6];
    const float* off_b = (const float*)d_in[7];
    const float* w2 = (const float*)d_in[8];
    const float* bn2g = (const float*)d_in[9];
    const float* bn2b = (const float*)d_in[10];
    const float* bn2m = (const float*)d_in[11];
    const float* bn2v = (const float*)d_in[12];
    const float* w3 = (const float*)d_in[13];
    const float* bn3g = (const float*)d_in[14];
    const float* bn3b = (const float*)d_in[15];
    const float* bn3m = (const float*)d_in[16];
    const float* bn3v = (const float*)d_in[17];
    float* out = (float*)d_out;

    char* ws = (char*)d_ws;
    float* bnc = (float*)(ws + 0);
    bf16_t* owtb = (bf16_t*)(ws + 12288);
    float* off = (float*)(ws + 178176);
    bf16_t* xb = (bf16_t*)(ws + 1357824);
    bf16_t* w1b = (bf16_t*)(ws + 34912256);
    bf16_t* w2fb = (bf16_t*)(ws + 35436544);
    bf16_t* w3b = (bf16_t*)(ws + 36616192);
    bf16_t* h1b = (bf16_t*)(ws + 37140480);
    bf16_t* h2b = (bf16_t*)(ws + 45529088);

    k_bnprep<<<1, 1024, 0, stream>>>(bn1g, bn1b, bn1m, bn1v, bn2g, bn2b, bn2m,
                                     bn2v, bn3g, bn3b, bn3m, bn3v, bnc);
    k_cast<<<256, 256, 0, stream>>>(w1, w1b, 65536);
    k_cast<<<256, 256, 0, stream>>>(w3, w3b, 65536);
    k_w2f<<<288, 256, 0, stream>>>(w2, w2fb);
    k_owtb<<<288, 256, 0, stream>>>(off_w, owtb);
    k_xb<<<dim3(16, 16, 16), 256, 0, stream>>>(x, xb);
    // conv1: M=16384 N=256 K=1024
    k_gemm64<<<dim3(256, 2), 256, 0, stream>>>(xb, w1b, 1024, 256, bnc,
                                               bnc + 256, nullptr, h1b, nullptr, 0);
    k_off<<<dim3(32, 16), 256, 0, stream>>>(h1b, owtb, off_b, off);
    k_deform<<<dim3(32, 16), 256, 0, stream>>>(h1b, off, w2fb, bnc, h2b);
    // conv3: M=16384 N=1024 K=256, residual + BN3 + ReLU -> out NCHW f32
    k_gemm64<<<dim3(256, 8), 256, 0, stream>>>(h2b, w3b, 256, 1024, bnc + 1024,
                                               bnc + 2048, x, nullptr, out, 1);
}

// Round 8
// 288.109 us; speedup vs baseline: 1.2441x; 1.0214x over previous
//
#include <hip/hip_runtime.h>

#define BN_EPS 1e-5f

typedef __bf16 bf16_t;
typedef __bf16 bf16x8 __attribute__((ext_vector_type(8)));
typedef float f32x4 __attribute__((ext_vector_type(4)));

// ws layout (bytes):
//   bnc   f32   3072 elems  @ 0
//   owtb  bf16  73728       @ 12288    [j pad32][kp 9][c 256]
//   (off  slot unused now)  @ 178176
//   xb    bf16  16777216    @ 1357824
//   w1b   bf16  262144      @ 34912256
//   w2fb  bf16  589824      @ 35436544   fragment order [kp][p][nt][lane][8]
//   w3b   bf16  262144      @ 36616192
//   h1b   bf16  4194304     @ 37140480   [b*hw][c=256]
//   h2b   bf16  4194304     @ 45529088
//   total ~51.4 MB

// ---------------- prep: BN scale/shift ----------------
__global__ void __launch_bounds__(1024) k_bnprep(
    const float* g1, const float* b1, const float* m1, const float* v1,
    const float* g2, const float* b2, const float* m2, const float* v2,
    const float* g3, const float* b3, const float* m3, const float* v3,
    float* bnc) {
    int t = threadIdx.x;
    if (t < 256) {
        float s = g1[t] * rsqrtf(v1[t] + BN_EPS);
        bnc[t] = s;
        bnc[256 + t] = b1[t] - m1[t] * s;
        float s2 = g2[t] * rsqrtf(v2[t] + BN_EPS);
        bnc[512 + t] = s2;
        bnc[768 + t] = b2[t] - m2[t] * s2;
    }
    float s3 = g3[t] * rsqrtf(v3[t] + BN_EPS);
    bnc[1024 + t] = s3;
    bnc[2048 + t] = b3[t] - m3[t] * s3;
}

// ---------------- prep: fp32 -> bf16 cast ----------------
__global__ void __launch_bounds__(256) k_cast(const float* __restrict__ s,
                                              bf16_t* __restrict__ d, int n4) {
    int i = blockIdx.x * 256 + threadIdx.x;
    if (i >= n4) return;
    float4 v = ((const float4*)s)[i];
    d[4 * i + 0] = (bf16_t)v.x;
    d[4 * i + 1] = (bf16_t)v.y;
    d[4 * i + 2] = (bf16_t)v.z;
    d[4 * i + 3] = (bf16_t)v.w;
}

// ---- prep: w2 (O,C,3,3) -> bf16 fragment order [kp][p][nt][lane][8] ----
__global__ void __launch_bounds__(256) k_w2f(const float* __restrict__ w2,
                                             bf16_t* __restrict__ w2f) {
    int idx = blockIdx.x * 256 + threadIdx.x; // 9*8*16*64 = 73728 groups
    if (idx >= 73728) return;
    int lane = idx & 63;
    int rest = idx >> 6;   // kp*128 + p*16 + nt
    int nt = rest & 15;
    int rest2 = rest >> 4; // kp*8 + p
    int p = rest2 & 7;
    int kp = rest2 >> 3;
    int n = nt * 16 + (lane & 15);
    int c0 = p * 32 + (lane >> 4) * 8;
    bf16x8 r;
#pragma unroll
    for (int e = 0; e < 8; ++e)
        r[e] = (bf16_t)w2[(size_t)n * 2304 + (c0 + e) * 9 + kp];
    *(bf16x8*)(w2f + (size_t)idx * 8) = r;
}

// ---------------- prep: off_w (18,C,3,3) -> bf16 [j pad32][kp][c], 0-pad ----
__global__ void __launch_bounds__(256) k_owtb(const float* __restrict__ ow,
                                              bf16_t* __restrict__ owtb) {
    int idx = blockIdx.x * 256 + threadIdx.x; // 32*9*256 = 73728
    if (idx >= 73728) return;
    int j = idx / 2304;
    int rem = idx - j * 2304;
    int kp = rem >> 8;
    int c = rem & 255;
    float v = (j < 18) ? ow[(j * 256 + c) * 9 + kp] : 0.f;
    owtb[idx] = (bf16_t)v;
}

// ---------------- prep: x NCHW f32 -> xb NHWC bf16 ----------------
__global__ void __launch_bounds__(256) k_xb(const float* __restrict__ x,
                                            bf16_t* __restrict__ xb) {
    __shared__ float ld[64 * 68];
    int t = threadIdx.x;
    int hw0 = blockIdx.x * 64, c0 = blockIdx.y * 64, b = blockIdx.z;
    int ci = t >> 2, h0 = (t & 3) * 16;
    const float* src = x + ((size_t)(b * 1024 + c0 + ci) << 10) + hw0 + h0;
#pragma unroll
    for (int i = 0; i < 4; ++i)
        *(float4*)(ld + ci * 68 + h0 + 4 * i) = *(const float4*)(src + 4 * i);
    __syncthreads();
    int r = t >> 2, cc0 = (t & 3) * 16;
    bf16x8 o0, o1;
#pragma unroll
    for (int i = 0; i < 8; ++i) o0[i] = (bf16_t)ld[(cc0 + i) * 68 + r];
#pragma unroll
    for (int i = 0; i < 8; ++i) o1[i] = (bf16_t)ld[(cc0 + 8 + i) * 68 + r];
    bf16_t* dst = xb + ((size_t)(b * 1024 + hw0 + r) << 10) + c0 + cc0;
    *(bf16x8*)dst = o0;
    *(bf16x8*)(dst + 8) = o1;
}

// ------- shared MFMA GEMM, pipelined: dbuf LDS, reg prefetch, 1 barrier/iter
// BM=64 BN=128 BK=32, 256 thr = 4 waves (2x2), wave: 32x64 (2x4 frags)
__global__ void __launch_bounds__(256) k_gemm64(
    const bf16_t* __restrict__ A, const bf16_t* __restrict__ Bt, int K, int ldo,
    const float* __restrict__ sc, const float* __restrict__ sh,
    const float* __restrict__ resid, bf16_t* __restrict__ outb,
    float* __restrict__ outf, int epi) {
    __shared__ __align__(16) bf16_t As[2][64 * 40];
    __shared__ __align__(16) bf16_t Bs[2][128 * 40];
    int t = threadIdx.x;
    int lane = t & 63;
    int w = t >> 6;
    int wm = w >> 1, wn = w & 1;
    int m0 = blockIdx.x * 64, n0 = blockIdx.y * 128;

    int ar = t >> 2, as_ = t & 3;
    const bf16_t* ag = A + (size_t)(m0 + ar) * K + as_ * 8;
    int aw = ar * 40 + ((as_ ^ (ar & 3)) * 8);
    int bn0 = t >> 2, bs_ = t & 3;
    const bf16_t* bg0 = Bt + (size_t)(n0 + bn0) * K + bs_ * 8;
    const bf16_t* bg1 = Bt + (size_t)(n0 + 64 + bn0) * K + bs_ * 8;
    int bw0 = bn0 * 40 + ((bs_ ^ (bn0 & 3)) * 8);
    int bw1 = (64 + bn0) * 40 + ((bs_ ^ (bn0 & 3)) * 8);

    int asel = lane >> 4;
    int ar0 = wm * 32 + (lane & 15);
    int aoff0 = ar0 * 40 + ((asel ^ (ar0 & 3)) * 8);
    int aoff1 = (ar0 + 16) * 40 + ((asel ^ (ar0 & 3)) * 8);
    int boff[4];
#pragma unroll
    for (int ni = 0; ni < 4; ++ni) {
        int n = wn * 64 + ni * 16 + (lane & 15);
        boff[ni] = n * 40 + ((asel ^ (n & 3)) * 8);
    }
    f32x4 acc[2][4] = {};

    // prologue: stage tile 0
    bf16x8 ra = *(const bf16x8*)(ag);
    bf16x8 rb0 = *(const bf16x8*)(bg0);
    bf16x8 rb1 = *(const bf16x8*)(bg1);
    *(bf16x8*)(As[0] + aw) = ra;
    *(bf16x8*)(Bs[0] + bw0) = rb0;
    *(bf16x8*)(Bs[0] + bw1) = rb1;
    __syncthreads();

    int nt = K >> 5;
    for (int ti = 0; ti < nt; ++ti) {
        int cur = ti & 1;
        if (ti + 1 < nt) { // issue next tile's loads early (latency under MFMA)
            ra = *(const bf16x8*)(ag + (ti + 1) * 32);
            rb0 = *(const bf16x8*)(bg0 + (ti + 1) * 32);
            rb1 = *(const bf16x8*)(bg1 + (ti + 1) * 32);
        }
        bf16x8 a0 = *(const bf16x8*)(As[cur] + aoff0);
        bf16x8 a1 = *(const bf16x8*)(As[cur] + aoff1);
#pragma unroll
        for (int ni = 0; ni < 4; ++ni) {
            bf16x8 bv = *(const bf16x8*)(Bs[cur] + boff[ni]);
            acc[0][ni] = __builtin_amdgcn_mfma_f32_16x16x32_bf16(a0, bv, acc[0][ni], 0, 0, 0);
            acc[1][ni] = __builtin_amdgcn_mfma_f32_16x16x32_bf16(a1, bv, acc[1][ni], 0, 0, 0);
        }
        if (ti + 1 < nt) { // write-late into the other buffer
            *(bf16x8*)(As[cur ^ 1] + aw) = ra;
            *(bf16x8*)(Bs[cur ^ 1] + bw0) = rb0;
            *(bf16x8*)(Bs[cur ^ 1] + bw1) = rb1;
        }
        __syncthreads();
    }

    int mrb = m0 + wm * 32 + (lane >> 4) * 4;
    int ncb = n0 + wn * 64 + (lane & 15);
    if (epi == 0) {
#pragma unroll
        for (int mi = 0; mi < 2; ++mi)
#pragma unroll
            for (int ni = 0; ni < 4; ++ni) {
                int n = ncb + ni * 16;
                float s = sc[n], h = sh[n];
#pragma unroll
                for (int j = 0; j < 4; ++j) {
                    int m = mrb + mi * 16 + j;
                    float v = fmaxf(fmaf(acc[mi][ni][j], s, h), 0.f);
                    outb[(size_t)m * ldo + n] = (bf16_t)v;
                }
            }
    } else {
#pragma unroll
        for (int mi = 0; mi < 2; ++mi) {
            int m = mrb + mi * 16;
            int bb = m >> 10, hw = m & 1023;
#pragma unroll
            for (int ni = 0; ni < 4; ++ni) {
                int o = ncb + ni * 16;
                float s = sc[o], h = sh[o];
                size_t idx = (((size_t)(bb * 1024 + o)) << 10) + hw;
                float4 r = *(const float4*)(resid + idx);
                float4 v;
                v.x = fmaxf(fmaf(acc[mi][ni][0], s, h) + r.x, 0.f);
                v.y = fmaxf(fmaf(acc[mi][ni][1], s, h) + r.y, 0.f);
                v.z = fmaxf(fmaf(acc[mi][ni][2], s, h) + r.z, 0.f);
                v.w = fmaxf(fmaf(acc[mi][ni][3], s, h) + r.w, 0.f);
                *(float4*)(outf + idx) = v;
            }
        }
    }
}

// ---------------- K3: fused offset-conv + deformable conv, MFMA ----------
// grid (32 y, 16 b), 256 thr = 4 waves.
// Prologue: in-block offset conv (same verified mapping as old k_off) ->
// offs[j][x] in LDS. Then per tap k: issue gather k+1, GEMM chunks 0-3
// (reg B dbuf), cvt+ds_write k+1 into As[other], GEMM 4-7, one barrier.
__global__ void __launch_bounds__(256) k_deform(const bf16_t* __restrict__ h1,
                                                const bf16_t* __restrict__ owtb,
                                                const float* __restrict__ offb,
                                                const bf16_t* __restrict__ w2f,
                                                const float* __restrict__ bnc,
                                                bf16_t* __restrict__ h2) {
    __shared__ __align__(16) bf16_t As[2][8 * 1288]; // 2 x 8 panels x ([32][40]+8)
    __shared__ float offs[18 * 33];                  // [j][x] pitch 33
    int t = threadIdx.x;
    int lane = t & 63;
    int wn = t >> 6;
    int y = blockIdx.x, b = blockIdx.y;
    int sx = t >> 3, scg = t & 7; // sample-build: row, c-group of 32
    int asel = lane >> 4;
    int ar0 = lane & 15;
    int aoff0 = ar0 * 40 + ((asel ^ (ar0 & 3)) * 8);
    int aoff1 = (ar0 + 16) * 40 + ((asel ^ ((ar0 + 16) & 3)) * 8);
    const bf16_t* wfl = w2f + (size_t)(wn * 256 + lane) * 8;
    f32x4 acc[2][4] = {};
    size_t h1row = (size_t)b * 1024;

    // ---- offset-conv prologue (M=32 x, N=32 j pad, K=2304) ----
    {
        int mi = wn >> 1, ni = wn & 1;
        int xq = (lane & 15) + mi * 16;
        int ks2 = lane >> 4;
        int jq = (lane & 15) + ni * 16;
        f32x4 oacc = {};
        const bf16_t* browq = owtb + (size_t)jq * 2304 + ks2 * 8;
        for (int kp = 0; kp < 9; ++kp) {
            int yy = y + kp / 3 - 1;
            int xx = xq + kp % 3 - 1;
            bool vv = (yy >= 0) && (yy < 32) && (xx >= 0) && (xx < 32);
            const bf16_t* arow = h1 + ((h1row + yy * 32 + xx) << 8) + ks2 * 8;
            const bf16_t* bp = browq + kp * 256;
#pragma unroll
            for (int s = 0; s < 8; ++s) {
                bf16x8 av = {};
                if (vv) av = *(const bf16x8*)(arow + s * 32);
                bf16x8 bv = *(const bf16x8*)(bp + s * 32);
                oacc = __builtin_amdgcn_mfma_f32_16x16x32_bf16(av, bv, oacc, 0, 0, 0);
            }
        }
        if (jq < 18) {
            float bias = offb[jq];
#pragma unroll
            for (int r = 0; r < 4; ++r)
                offs[jq * 33 + mi * 16 + ks2 * 4 + r] = oacc[r] + bias;
        }
    }
    __syncthreads();

    // pending-tap gather state (held in regs across the GEMM)
    bf16x8 g00[4], g01[4], g10[4], g11[4];
    float w00, w01, w10, w11;

    auto issue_gather = [&](int k) {
        float oy = offs[(2 * k) * 33 + sx];
        float ox = offs[(2 * k + 1) * 33 + sx];
        float py = (float)y + (float)(k / 3 - 1) + oy;
        float px = (float)sx + (float)(k % 3 - 1) + ox;
        float fy = floorf(py), fx = floorf(px);
        float wy = py - fy, wx = px - fx;
        int y0 = (int)fy, x0 = (int)fx;
        int y1 = y0 + 1, x1 = x0 + 1;
        float vy0 = (y0 >= 0 && y0 < 32) ? 1.f : 0.f;
        float vy1 = (y1 >= 0 && y1 < 32) ? 1.f : 0.f;
        float vx0 = (x0 >= 0 && x0 < 32) ? 1.f : 0.f;
        float vx1 = (x1 >= 0 && x1 < 32) ? 1.f : 0.f;
        int yc0 = min(max(y0, 0), 31), yc1 = min(max(y1, 0), 31);
        int xc0 = min(max(x0, 0), 31), xc1 = min(max(x1, 0), 31);
        w00 = (1.f - wy) * (1.f - wx) * vy0 * vx0;
        w01 = (1.f - wy) * wx * vy0 * vx1;
        w10 = wy * (1.f - wx) * vy1 * vx0;
        w11 = wy * wx * vy1 * vx1;
        const bf16_t* p00 = h1 + ((h1row + yc0 * 32 + xc0) << 8);
        const bf16_t* p01 = h1 + ((h1row + yc0 * 32 + xc1) << 8);
        const bf16_t* p10 = h1 + ((h1row + yc1 * 32 + xc0) << 8);
        const bf16_t* p11 = h1 + ((h1row + yc1 * 32 + xc1) << 8);
#pragma unroll
        for (int q = 0; q < 4; ++q) {
            int c = scg * 32 + q * 8;
            g00[q] = *(const bf16x8*)(p00 + c);
            g01[q] = *(const bf16x8*)(p01 + c);
            g10[q] = *(const bf16x8*)(p10 + c);
            g11[q] = *(const bf16x8*)(p11 + c);
        }
    };
    auto cvt_write = [&](int buf) {
        bf16_t* pnl = &As[buf][scg * 1288 + sx * 40];
#pragma unroll
        for (int q = 0; q < 4; ++q) {
            bf16x8 r;
#pragma unroll
            for (int e = 0; e < 8; ++e) {
                float f = w00 * (float)g00[q][e] + w01 * (float)g01[q][e] +
                          w10 * (float)g10[q][e] + w11 * (float)g11[q][e];
                r[e] = (bf16_t)f;
            }
            *(bf16x8*)(pnl + ((q ^ (sx & 3)) * 8)) = r;
        }
    };

    // prologue: fill buffer 0 for tap 0
    issue_gather(0);
    cvt_write(0);
    __syncthreads();

    for (int k = 0; k < 9; ++k) {
        int cur = k & 1;
        if (k < 8) issue_gather(k + 1); // loads in flight across GEMM
        const bf16_t* wfk = wfl + (size_t)k * 65536;
        bf16x8 bb[2][4];
#pragma unroll
        for (int ni = 0; ni < 4; ++ni)
            bb[0][ni] = *(const bf16x8*)(wfk + ni * 512);
#pragma unroll
        for (int ni = 0; ni < 4; ++ni)
            bb[1][ni] = *(const bf16x8*)(wfk + 8192 + ni * 512);
        // chunks 0..3
#pragma unroll
        for (int p = 0; p < 4; ++p) {
            const bf16_t* pb = &As[cur][p * 1288];
            bf16x8 a0 = *(const bf16x8*)(pb + aoff0);
            bf16x8 a1 = *(const bf16x8*)(pb + aoff1);
#pragma unroll
            for (int ni = 0; ni < 4; ++ni) {
                bf16x8 bv = bb[p & 1][ni];
                acc[0][ni] = __builtin_amdgcn_mfma_f32_16x16x32_bf16(a0, bv, acc[0][ni], 0, 0, 0);
                acc[1][ni] = __builtin_amdgcn_mfma_f32_16x16x32_bf16(a1, bv, acc[1][ni], 0, 0, 0);
            }
#pragma unroll
            for (int ni = 0; ni < 4; ++ni)
                bb[p & 1][ni] = *(const bf16x8*)(wfk + (p + 2) * 8192 + ni * 512);
        }
        // overlap: convert + stage next tap's samples into the other buffer
        if (k < 8) cvt_write(cur ^ 1);
        // chunks 4..7
#pragma unroll
        for (int p = 4; p < 8; ++p) {
            const bf16_t* pb = &As[cur][p * 1288];
            bf16x8 a0 = *(const bf16x8*)(pb + aoff0);
            bf16x8 a1 = *(const bf16x8*)(pb + aoff1);
#pragma unroll
            for (int ni = 0; ni < 4; ++ni) {
                bf16x8 bv = bb[p & 1][ni];
                acc[0][ni] = __builtin_amdgcn_mfma_f32_16x16x32_bf16(a0, bv, acc[0][ni], 0, 0, 0);
                acc[1][ni] = __builtin_amdgcn_mfma_f32_16x16x32_bf16(a1, bv, acc[1][ni], 0, 0, 0);
            }
            if (p + 2 < 8) {
#pragma unroll
                for (int ni = 0; ni < 4; ++ni)
                    bb[p & 1][ni] = *(const bf16x8*)(wfk + (p + 2) * 8192 + ni * 512);
            }
        }
        __syncthreads(); // writes to cur^1 visible; all reads of cur done
    }
    // epilogue: BN2 + ReLU -> h2 bf16
    int mrb = (lane >> 4) * 4;
    int ncb = wn * 64 + (lane & 15);
#pragma unroll
    for (int mi = 0; mi < 2; ++mi)
#pragma unroll
        for (int ni = 0; ni < 4; ++ni) {
            int n = ncb + ni * 16;
            float s = bnc[512 + n], h = bnc[768 + n];
#pragma unroll
            for (int j = 0; j < 4; ++j) {
                int row = mrb + mi * 16 + j;
                float v = fmaxf(fmaf(acc[mi][ni][j], s, h), 0.f);
                h2[(((size_t)(b * 1024 + y * 32 + row)) << 8) + n] = (bf16_t)v;
            }
        }
}

extern "C" void kernel_launch(void* const* d_in, const int* in_sizes, int n_in,
                              void* d_out, int out_size, void* d_ws, size_t ws_size,
                              hipStream_t stream) {
    const float* x = (const float*)d_in[0];
    const float* w1 = (const float*)d_in[1];
    const float* bn1g = (const float*)d_in[2];
    const float* bn1b = (const float*)d_in[3];
    const float* bn1m = (const float*)d_in[4];
    const float* bn1v = (const float*)d_in[5];
    const float* off_w = (const float*)d_in[6];
    const float* off_b = (const float*)d_in[7];
    const float* w2 = (const float*)d_in[8];
    const float* bn2g = (const float*)d_in[9];
    const float* bn2b = (const float*)d_in[10];
    const float* bn2m = (const float*)d_in[11];
    const float* bn2v = (const float*)d_in[12];
    const float* w3 = (const float*)d_in[13];
    const float* bn3g = (const float*)d_in[14];
    const float* bn3b = (const float*)d_in[15];
    const float* bn3m = (const float*)d_in[16];
    const float* bn3v = (const float*)d_in[17];
    float* out = (float*)d_out;

    char* ws = (char*)d_ws;
    float* bnc = (float*)(ws + 0);
    bf16_t* owtb = (bf16_t*)(ws + 12288);
    bf16_t* xb = (bf16_t*)(ws + 1357824);
    bf16_t* w1b = (bf16_t*)(ws + 34912256);
    bf16_t* w2fb = (bf16_t*)(ws + 35436544);
    bf16_t* w3b = (bf16_t*)(ws + 36616192);
    bf16_t* h1b = (bf16_t*)(ws + 37140480);
    bf16_t* h2b = (bf16_t*)(ws + 45529088);

    k_bnprep<<<1, 1024, 0, stream>>>(bn1g, bn1b, bn1m, bn1v, bn2g, bn2b, bn2m,
                                     bn2v, bn3g, bn3b, bn3m, bn3v, bnc);
    k_cast<<<256, 256, 0, stream>>>(w1, w1b, 65536);
    k_cast<<<256, 256, 0, stream>>>(w3, w3b, 65536);
    k_w2f<<<288, 256, 0, stream>>>(w2, w2fb);
    k_owtb<<<288, 256, 0, stream>>>(off_w, owtb);
    k_xb<<<dim3(16, 16, 16), 256, 0, stream>>>(x, xb);
    // conv1: M=16384 N=256 K=1024
    k_gemm64<<<dim3(256, 2), 256, 0, stream>>>(xb, w1b, 1024, 256, bnc,
                                               bnc + 256, nullptr, h1b, nullptr, 0);
    // fused offset-conv + deformable conv
    k_deform<<<dim3(32, 16), 256, 0, stream>>>(h1b, owtb, off_b, w2fb, bnc, h2b);
    // conv3: M=16384 N=1024 K=256, residual + BN3 + ReLU -> out NCHW f32
    k_gemm64<<<dim3(256, 8), 256, 0, stream>>>(h2b, w3b, 256, 1024, bnc + 1024,
                                               bnc + 2048, x, nullptr, out, 1);
}